// Round 1
// baseline (879.070 us; speedup 1.0000x reference)
//
#include <hip/hip_runtime.h>
#include <math.h>

#define B_   8
#define C_   32
#define H_   512
#define W_   512
#define CQ_  8
#define WS_  8
#define NW_  4096          // windows per batch = (H/8)*(W/8)
#define ED_  2048
#define EH_  1024          // ED/2
#define EPS_ 1e-6f

#define TW 32
#define TH 8
#define HALO_W (TW + 2)            // 34
#define HALO_H (TH + 2)            // 10
#define HALO_N (HALO_W * HALO_H)   // 340

__device__ __forceinline__ float leaky(float x) { return x > 0.f ? x : 0.1f * x; }

// ---------------------------------------------------------------------------
// Pass A: fused in_conv / conv+LN / SA 3x3 conv / window variance / pooled sum
// grid (W/32, H/8, B), block 256
// ---------------------------------------------------------------------------
__global__ __launch_bounds__(256) void pass_a(
    const float* __restrict__ x,
    const float* __restrict__ w_in, const float* __restrict__ b_in,
    const float* __restrict__ w_conv, const float* __restrict__ b_conv,
    const float* __restrict__ ln_w, const float* __restrict__ ln_b,
    const float* __restrict__ w_sa, const float* __restrict__ b_sa,
    float* __restrict__ sa_out, double* __restrict__ var_out,
    float* __restrict__ pooled)
{
    __shared__ float2 s_w[CQ_ * C_];                 // (w_conv, w_in) packed
    __shared__ float  s_bin[CQ_], s_bcv[CQ_], s_lnw[CQ_], s_lnb[CQ_];
    __shared__ float  s_wsa[CQ_ * 9];
    __shared__ float  xl[CQ_][HALO_H][HALO_W];       // x_ tile + halo
    __shared__ float  xm_lds[TH][TW];                // window-mean of in_conv branch

    const int tid = threadIdx.x;
    const int b   = blockIdx.z;
    const int ty  = blockIdx.y * TH;
    const int tx  = blockIdx.x * TW;

    if (tid < CQ_ * C_) s_w[tid] = make_float2(w_conv[tid], w_in[tid]);
    if (tid >= 0 && tid < CQ_) {
        s_bin[tid] = b_in[tid]; s_bcv[tid] = b_conv[tid];
        s_lnw[tid] = ln_w[tid]; s_lnb[tid] = ln_b[tid];
    }
    if (tid >= 64 && tid < 64 + CQ_ * 9) s_wsa[tid - 64] = w_sa[tid - 64];
    __syncthreads();

    const size_t plane = (size_t)H_ * W_;
    const float* xb = x + (size_t)b * C_ * plane;

    // two halo positions per thread (340 positions, 256 threads)
    const int idx0 = tid, idx1 = tid + 256;
    const int hy0 = idx0 / HALO_W, hx0 = idx0 % HALO_W;
    const int hy1 = idx1 / HALO_W, hx1 = idx1 % HALO_W;
    const bool has1 = (idx1 < HALO_N);
    const int gy0 = ty + hy0 - 1, gx0 = tx + hx0 - 1;
    const int gy1 = ty + hy1 - 1, gx1 = tx + hx1 - 1;
    const bool ib0 = (gy0 >= 0 && gy0 < H_ && gx0 >= 0 && gx0 < W_);
    const bool ib1 = has1 && (gy1 >= 0 && gy1 < H_ && gx1 >= 0 && gx1 < W_);

    const float* p0 = ib0 ? (xb + (size_t)gy0 * W_ + gx0) : xb;
    const float* p1 = ib1 ? (xb + (size_t)gy1 * W_ + gx1) : xb;

    float ycv0[CQ_], yin0[CQ_], ycv1[CQ_], yin1[CQ_];
#pragma unroll
    for (int q = 0; q < CQ_; ++q) { ycv0[q]=0.f; yin0[q]=0.f; ycv1[q]=0.f; yin1[q]=0.f; }

#pragma unroll 8
    for (int c = 0; c < C_; ++c) {
        const float v0 = p0[(size_t)c * plane];
        const float v1 = p1[(size_t)c * plane];
#pragma unroll
        for (int q = 0; q < CQ_; ++q) {
            const float2 w = s_w[q * C_ + c];
            ycv0[q] = fmaf(w.x, v0, ycv0[q]);
            yin0[q] = fmaf(w.y, v0, yin0[q]);
            ycv1[q] = fmaf(w.x, v1, ycv1[q]);
            yin1[q] = fmaf(w.y, v1, yin1[q]);
        }
    }

    // ---- position 0 ----
    {
        if (ib0) {
            float u = 0.f;
#pragma unroll
            for (int q = 0; q < CQ_; ++q) { ycv0[q] += s_bcv[q]; u += ycv0[q]; }
            u *= (1.f / CQ_);
            float s = 0.f;
#pragma unroll
            for (int q = 0; q < CQ_; ++q) { const float d = ycv0[q] - u; s = fmaf(d, d, s); }
            s *= (1.f / CQ_);
            const float inv = 1.f / sqrtf(s + EPS_);
#pragma unroll
            for (int q = 0; q < CQ_; ++q)
                xl[q][hy0][hx0] = leaky(fmaf(s_lnw[q], (ycv0[q] - u) * inv, s_lnb[q]));
        } else {
#pragma unroll
            for (int q = 0; q < CQ_; ++q) xl[q][hy0][hx0] = 0.f;
        }
        if (hy0 >= 1 && hy0 <= TH && hx0 >= 1 && hx0 <= TW) {
            float m = 0.f;
#pragma unroll
            for (int q = 0; q < CQ_; ++q) m += leaky(yin0[q] + s_bin[q]);
            xm_lds[hy0 - 1][hx0 - 1] = m * (1.f / CQ_);
        }
    }
    // ---- position 1 ----
    if (has1) {
        if (ib1) {
            float u = 0.f;
#pragma unroll
            for (int q = 0; q < CQ_; ++q) { ycv1[q] += s_bcv[q]; u += ycv1[q]; }
            u *= (1.f / CQ_);
            float s = 0.f;
#pragma unroll
            for (int q = 0; q < CQ_; ++q) { const float d = ycv1[q] - u; s = fmaf(d, d, s); }
            s *= (1.f / CQ_);
            const float inv = 1.f / sqrtf(s + EPS_);
#pragma unroll
            for (int q = 0; q < CQ_; ++q)
                xl[q][hy1][hx1] = leaky(fmaf(s_lnw[q], (ycv1[q] - u) * inv, s_lnb[q]));
        } else {
#pragma unroll
            for (int q = 0; q < CQ_; ++q) xl[q][hy1][hx1] = 0.f;
        }
        if (hy1 >= 1 && hy1 <= TH && hx1 >= 1 && hx1 <= TW) {
            float m = 0.f;
#pragma unroll
            for (int q = 0; q < CQ_; ++q) m += leaky(yin1[q] + s_bin[q]);
            xm_lds[hy1 - 1][hx1 - 1] = m * (1.f / CQ_);
        }
    }

    __syncthreads();

    // ---- spatial attention: 3x3 conv over 8 channels + sigmoid ----
    {
        const int py = tid >> 5, px = tid & 31;
        float acc = b_sa[0];
#pragma unroll
        for (int q = 0; q < CQ_; ++q) {
#pragma unroll
            for (int ky = 0; ky < 3; ++ky) {
#pragma unroll
                for (int kx = 0; kx < 3; ++kx)
                    acc = fmaf(s_wsa[q * 9 + ky * 3 + kx], xl[q][py + ky][px + kx], acc);
            }
        }
        const float sa = 1.f / (1.f + expf(-acc));
        sa_out[((size_t)b * H_ + (ty + py)) * W_ + (tx + px)] = sa;
    }

    const int wave = tid >> 6, lane = tid & 63;

    // ---- pooled sum of x_ (wave w reduces channels 2w, 2w+1) ----
    {
        float s0 = 0.f, s1 = 0.f;
        const int q0 = wave * 2, q1 = q0 + 1;
#pragma unroll
        for (int k = 0; k < 4; ++k) {
            const int pix = lane + 64 * k;
            const int py = pix >> 5, px = pix & 31;
            s0 += xl[q0][py + 1][px + 1];
            s1 += xl[q1][py + 1][px + 1];
        }
#pragma unroll
        for (int off = 32; off; off >>= 1) {
            s0 += __shfl_xor(s0, off);
            s1 += __shfl_xor(s1, off);
        }
        if (lane == 0) {
            atomicAdd(&pooled[b * CQ_ + q0], s0);
            atomicAdd(&pooled[b * CQ_ + q1], s1);
        }
    }

    // ---- window variance (ddof=1), double precision; wave w = window w ----
    {
        const int ly = lane >> 3, lx = lane & 7;
        const double dv = (double)xm_lds[ly][wave * 8 + lx];
        double s = dv;
#pragma unroll
        for (int off = 32; off; off >>= 1) s += __shfl_xor(s, off);
        const double mean = s * (1.0 / 64.0);
        const double d = dv - mean;
        double s2 = d * d;
#pragma unroll
        for (int off = 32; off; off >>= 1) s2 += __shfl_xor(s2, off);
        if (lane == 0) {
            const int n = blockIdx.y * (W_ / WS_) + blockIdx.x * 4 + wave;
            var_out[(size_t)b * NW_ + n] = s2 * (1.0 / 63.0);
        }
    }
}

// ---------------------------------------------------------------------------
// Channel attention: pooled mean -> 1x1 conv -> sigmoid. 1 block, 256 = B*C.
// ---------------------------------------------------------------------------
__global__ void ca_kernel(const float* __restrict__ pooled,
                          const float* __restrict__ w_ca, const float* __restrict__ b_ca,
                          float* __restrict__ ca_out)
{
    const int t = threadIdx.x;
    const int b = t >> 5, o = t & 31;
    float acc = b_ca[o];
#pragma unroll
    for (int q = 0; q < CQ_; ++q)
        acc = fmaf(w_ca[o * CQ_ + q], pooled[b * CQ_ + q] * (1.f / ((float)H_ * (float)W_)), acc);
    ca_out[t] = 1.f / (1.f + expf(-acc));
}

// ---------------------------------------------------------------------------
// Exact bottom-k selection via rank, top_k-stable tie-break. grid (16, B)
// ---------------------------------------------------------------------------
__global__ __launch_bounds__(256) void mask_rank(const double* __restrict__ var,
                                                 float* __restrict__ maskF)
{
    __shared__ double sv[NW_];   // 32 KB
    const int b = blockIdx.y;
    const int tid = threadIdx.x;
    const double* vb = var + (size_t)b * NW_;
    for (int j = tid; j < NW_; j += 256) sv[j] = vb[j];
    __syncthreads();

    const int i = blockIdx.x * 256 + tid;
    const double vi = sv[i];
    int cnt = 0;
#pragma unroll 4
    for (int j = 0; j < NW_; ++j) {
        const double vj = sv[j];
        cnt += (vj < vi) || (vj == vi && j < i);
    }
    maskF[(size_t)b * NW_ + i] = (cnt < NW_ / 2) ? 0.f : 1.f;
}

// ---------------------------------------------------------------------------
// h1[e] = leaky(rowsum(w_m1[e,:]) + b_m1[e]);  h0[e] = leaky(b_m1[e])
// wave per row; grid 256 x 256 threads
// ---------------------------------------------------------------------------
__global__ __launch_bounds__(256) void h_kernel(const float* __restrict__ w_m1,
                                                const float* __restrict__ b_m1,
                                                float* __restrict__ h1, float* __restrict__ h0)
{
    const int wave = threadIdx.x >> 6, lane = threadIdx.x & 63;
    const int e = blockIdx.x * 4 + wave;
    const float* row = w_m1 + (size_t)e * ED_;
    float s = 0.f;
#pragma unroll
    for (int k = 0; k < ED_ / 64; ++k) s += row[lane + 64 * k];
#pragma unroll
    for (int off = 32; off; off >>= 1) s += __shfl_xor(s, off);
    if (lane == 0) {
        h1[e] = leaky(s + b_m1[e]);
        h0[e] = leaky(b_m1[e]);
    }
}

// ---------------------------------------------------------------------------
// o1[f] = w_m2[f,:]*h1 + b_m2[f];  o0[f] = w_m2[f,:]*h0 + b_m2[f]
// wave per row; grid 512 x 256 threads
// ---------------------------------------------------------------------------
__global__ __launch_bounds__(256) void o_kernel(const float* __restrict__ w_m2,
                                                const float* __restrict__ b_m2,
                                                const float* __restrict__ h1,
                                                const float* __restrict__ h0,
                                                float* __restrict__ o1, float* __restrict__ o0)
{
    const int wave = threadIdx.x >> 6, lane = threadIdx.x & 63;
    const int f = blockIdx.x * 4 + wave;
    const float* row = w_m2 + (size_t)f * EH_;
    float s1 = 0.f, s0 = 0.f;
#pragma unroll
    for (int k = 0; k < EH_ / 64; ++k) {
        const float w = row[lane + 64 * k];
        s1 = fmaf(w, h1[lane + 64 * k], s1);
        s0 = fmaf(w, h0[lane + 64 * k], s0);
    }
#pragma unroll
    for (int off = 32; off; off >>= 1) {
        s1 += __shfl_xor(s1, off);
        s0 += __shfl_xor(s0, off);
    }
    if (lane == 0) {
        o1[f] = s1 + b_m2[f];
        o0[f] = s0 + b_m2[f];
    }
}

// ---------------------------------------------------------------------------
// out_mask row = mask ? o1 : o0.  grid = B*NW rows, 256 threads, float4 x2
// ---------------------------------------------------------------------------
__global__ __launch_bounds__(256) void bcast_kernel(const float* __restrict__ maskF,
                                                    const float* __restrict__ o1,
                                                    const float* __restrict__ o0,
                                                    float* __restrict__ out)
{
    const int row = blockIdx.x;
    const float4* src = (maskF[row] > 0.5f) ? (const float4*)o1 : (const float4*)o0;
    float4* dst = (float4*)(out + (size_t)row * ED_);
    const int t = threadIdx.x;
    dst[t]       = src[t];
    dst[t + 256] = src[t + 256];
}

__global__ void zero_kernel(float* __restrict__ p) { p[threadIdx.x] = 0.f; }

extern "C" void kernel_launch(void* const* d_in, const int* in_sizes, int n_in,
                              void* d_out, int out_size, void* d_ws, size_t ws_size,
                              hipStream_t stream)
{
    const float* x    = (const float*)d_in[0];
    const float* w_in = (const float*)d_in[1];
    const float* b_in = (const float*)d_in[2];
    const float* w_cv = (const float*)d_in[3];
    const float* b_cv = (const float*)d_in[4];
    const float* lnw  = (const float*)d_in[5];
    const float* lnb  = (const float*)d_in[6];
    const float* w_ca = (const float*)d_in[7];
    const float* b_ca = (const float*)d_in[8];
    const float* w_sa = (const float*)d_in[9];
    const float* b_sa = (const float*)d_in[10];
    const float* w_m1 = (const float*)d_in[11];
    const float* b_m1 = (const float*)d_in[12];
    const float* w_m2 = (const float*)d_in[13];
    const float* b_m2 = (const float*)d_in[14];

    float* out_mask = (float*)d_out;                           // [B, NW, ED]
    float* ca_out   = out_mask + (size_t)B_ * NW_ * ED_;       // [B, C]
    float* sa_out   = ca_out + (size_t)B_ * C_;                // [B, H, W]

    char* ws = (char*)d_ws;
    double* var   = (double*)ws;                               // B*NW doubles = 256 KB
    float* maskF  = (float*)(ws + (size_t)B_ * NW_ * 8);       // 128 KB
    float* pooled = maskF + (size_t)B_ * NW_;                  // 64 floats
    float* h1 = pooled + 64;
    float* h0 = h1 + EH_;
    float* o1 = h0 + EH_;
    float* o0 = o1 + ED_;

    zero_kernel<<<1, 64, 0, stream>>>(pooled);
    pass_a<<<dim3(W_ / TW, H_ / TH, B_), 256, 0, stream>>>(
        x, w_in, b_in, w_cv, b_cv, lnw, lnb, w_sa, b_sa, sa_out, var, pooled);
    ca_kernel<<<1, 256, 0, stream>>>(pooled, w_ca, b_ca, ca_out);
    mask_rank<<<dim3(NW_ / 256, B_), 256, 0, stream>>>(var, maskF);
    h_kernel<<<EH_ / 4, 256, 0, stream>>>(w_m1, b_m1, h1, h0);
    o_kernel<<<ED_ / 4, 256, 0, stream>>>(w_m2, b_m2, h1, h0, o1, o0);
    bcast_kernel<<<B_ * NW_, 256, 0, stream>>>(maskF, o1, o0, out_mask);
}

// Round 2
// 324.523 us; speedup vs baseline: 2.7088x; 2.7088x over previous
//
#include <hip/hip_runtime.h>
#include <math.h>

#define B_   8
#define C_   32
#define H_   512
#define W_   512
#define CQ_  8
#define NW_  4096          // windows per batch
#define ED_  2048
#define EH_  1024
#define EPS_ 1e-6f

#define TW 64
#define TH 16
#define XLH 18             // TH + 2 halo rows
#define XLW 68             // TW + 2 halo cols, padded to keep rows 16B-aligned

__device__ __forceinline__ float leaky(float x) { return x > 0.f ? x : 0.1f * x; }
__device__ __forceinline__ float sigmoidf_(float x) { return 1.f / (1.f + __expf(-x)); }

// ---------------------------------------------------------------------------
// Pass A (fused): both 1x1 convs, LN+leaky, SA 3x3 conv, window variance,
// pooled partial sums.  grid (8, 32, 8), block 256, 4 px/thread (float4).
// ---------------------------------------------------------------------------
__global__ __launch_bounds__(256) void pass_a(
    const float* __restrict__ x,
    const float* __restrict__ w_in, const float* __restrict__ b_in,
    const float* __restrict__ w_conv, const float* __restrict__ b_conv,
    const float* __restrict__ ln_w, const float* __restrict__ ln_b,
    const float* __restrict__ w_sa, const float* __restrict__ b_sa,
    float* __restrict__ sa_out, double* __restrict__ var_out,
    float* __restrict__ pooled_part)
{
    __shared__ float xl[CQ_][XLH][XLW];      // x_ tile + halo  (~38 KB)
    __shared__ float xm_lds[TH][TW];         // in_conv channel-mean (4 KB)
    __shared__ float red[4][CQ_];

    const int tid = threadIdx.x;
    const int b  = blockIdx.z;
    const int ty = blockIdx.y * TH, tx = blockIdx.x * TW;
    const int px = (tid & 15) * 4, py = tid >> 4;
    const size_t plane = (size_t)H_ * W_;
    const float* xb = x + (size_t)b * C_ * plane;

    // ---- interior: 4 consecutive pixels per thread, vectorized loads ----
    float ycv[CQ_][4], yin[CQ_][4];
#pragma unroll
    for (int q = 0; q < CQ_; ++q)
#pragma unroll
        for (int j = 0; j < 4; ++j) { ycv[q][j] = 0.f; yin[q][j] = 0.f; }

    const float* p = xb + (size_t)(ty + py) * W_ + (tx + px);
#pragma unroll 8
    for (int c = 0; c < C_; ++c) {
        const float4 v = *reinterpret_cast<const float4*>(p + (size_t)c * plane);
        const float vv[4] = {v.x, v.y, v.z, v.w};
#pragma unroll
        for (int q = 0; q < CQ_; ++q) {
            const float wc = w_conv[q * C_ + c];   // uniform -> s_load
            const float wi = w_in[q * C_ + c];     // uniform -> s_load
#pragma unroll
            for (int j = 0; j < 4; ++j) {
                ycv[q][j] = fmaf(wc, vv[j], ycv[q][j]);
                yin[q][j] = fmaf(wi, vv[j], yin[q][j]);
            }
        }
    }

#pragma unroll
    for (int q = 0; q < CQ_; ++q) {
        const float bc = b_conv[q];
#pragma unroll
        for (int j = 0; j < 4; ++j) ycv[q][j] += bc;
    }

    float ps[CQ_];
#pragma unroll
    for (int q = 0; q < CQ_; ++q) ps[q] = 0.f;

    float xmv[4];
#pragma unroll
    for (int j = 0; j < 4; ++j) {
        float u = 0.f;
#pragma unroll
        for (int q = 0; q < CQ_; ++q) u += ycv[q][j];
        u *= 0.125f;
        float s = 0.f;
#pragma unroll
        for (int q = 0; q < CQ_; ++q) { const float d = ycv[q][j] - u; s = fmaf(d, d, s); }
        s *= 0.125f;
        const float inv = 1.f / sqrtf(s + EPS_);
        float m = 0.f;
#pragma unroll
        for (int q = 0; q < CQ_; ++q) {
            const float xv = leaky(fmaf(ln_w[q], (ycv[q][j] - u) * inv, ln_b[q]));
            ycv[q][j] = xv;          // now holds x_
            ps[q] += xv;
            m += leaky(yin[q][j] + b_in[q]);
        }
        xmv[j] = m * 0.125f;
    }

    *reinterpret_cast<float4*>(&xm_lds[py][px]) = make_float4(xmv[0], xmv[1], xmv[2], xmv[3]);
#pragma unroll
    for (int q = 0; q < CQ_; ++q) {
        *reinterpret_cast<float2*>(&xl[q][py + 1][px + 2]) = make_float2(ycv[q][0], ycv[q][1]);
        *reinterpret_cast<float2*>(&xl[q][py + 1][px + 4]) = make_float2(ycv[q][2], ycv[q][3]);
    }

    const int lane = tid & 63, wave = tid >> 6;
    // pooled partial: wave-reduce 8 channel sums
#pragma unroll
    for (int q = 0; q < CQ_; ++q) {
        float s = ps[q];
#pragma unroll
        for (int off = 32; off; off >>= 1) s += __shfl_xor(s, off);
        if (lane == 0) red[wave][q] = s;
    }

    // ---- halo ring (164 positions): scalar path, x_ only ----
    if (tid < 164) {
        int hy, hx;
        if (tid < 66)       { hy = 0;              hx = tid + 1; }
        else if (tid < 132) { hy = 17;             hx = tid - 66 + 1; }
        else if (tid < 148) { hy = tid - 132 + 1;  hx = 1; }
        else                { hy = tid - 148 + 1;  hx = 66; }
        const int gy = ty + hy - 1, gx = tx + hx - 2;
        const bool inb = (gy >= 0 && gy < H_ && gx >= 0 && gx < W_);
        float yc[CQ_];
#pragma unroll
        for (int q = 0; q < CQ_; ++q) yc[q] = 0.f;
        if (inb) {
            const float* ph = xb + (size_t)gy * W_ + gx;
#pragma unroll 8
            for (int c = 0; c < C_; ++c) {
                const float v = ph[(size_t)c * plane];
#pragma unroll
                for (int q = 0; q < CQ_; ++q) yc[q] = fmaf(w_conv[q * C_ + c], v, yc[q]);
            }
            float u = 0.f;
#pragma unroll
            for (int q = 0; q < CQ_; ++q) { yc[q] += b_conv[q]; u += yc[q]; }
            u *= 0.125f;
            float s = 0.f;
#pragma unroll
            for (int q = 0; q < CQ_; ++q) { const float d = yc[q] - u; s = fmaf(d, d, s); }
            s *= 0.125f;
            const float inv = 1.f / sqrtf(s + EPS_);
#pragma unroll
            for (int q = 0; q < CQ_; ++q)
                yc[q] = leaky(fmaf(ln_w[q], (yc[q] - u) * inv, ln_b[q]));
        }
#pragma unroll
        for (int q = 0; q < CQ_; ++q) xl[q][hy][hx] = yc[q];
    }

    __syncthreads();

    // ---- pooled partial store ----
    if (tid < CQ_) {
        const float s = red[0][tid] + red[1][tid] + red[2][tid] + red[3][tid];
        const int bid = (blockIdx.z * gridDim.y + blockIdx.y) * gridDim.x + blockIdx.x;
        pooled_part[bid * CQ_ + tid] = s;
    }

    // ---- spatial attention 3x3 conv + sigmoid ----
    {
        const float bsa = b_sa[0];
        float acc[4] = {bsa, bsa, bsa, bsa};
#pragma unroll
        for (int q = 0; q < CQ_; ++q) {
#pragma unroll
            for (int dy = 0; dy < 3; ++dy) {
                const float* r = &xl[q][py + dy][px];
                const float4 aa = *reinterpret_cast<const float4*>(r);
                const float4 bb = *reinterpret_cast<const float4*>(r + 4);
                const float v[8] = {aa.x, aa.y, aa.z, aa.w, bb.x, bb.y, bb.z, bb.w};
#pragma unroll
                for (int dx = 0; dx < 3; ++dx) {
                    const float w = w_sa[q * 9 + dy * 3 + dx];   // uniform -> s_load
#pragma unroll
                    for (int j = 0; j < 4; ++j) acc[j] = fmaf(w, v[j + dx + 1], acc[j]);
                }
            }
        }
        const float4 o = make_float4(sigmoidf_(acc[0]), sigmoidf_(acc[1]),
                                     sigmoidf_(acc[2]), sigmoidf_(acc[3]));
        *reinterpret_cast<float4*>(&sa_out[((size_t)b * H_ + (ty + py)) * W_ + tx + px]) = o;
    }

    // ---- window variance (ddof=1, double), 16 windows/block, 4 per wave ----
#pragma unroll
    for (int k = 0; k < 4; ++k) {
        const int wi = wave * 4 + k;
        const int wy = wi >> 3, wx = wi & 7;
        const double dv = (double)xm_lds[wy * 8 + (lane >> 3)][wx * 8 + (lane & 7)];
        double s = dv;
#pragma unroll
        for (int off = 32; off; off >>= 1) s += __shfl_xor(s, off);
        const double mean = s * (1.0 / 64.0);
        const double d = dv - mean;
        double s2 = d * d;
#pragma unroll
        for (int off = 32; off; off >>= 1) s2 += __shfl_xor(s2, off);
        if (lane == 0) {
            const int n = (blockIdx.y * 2 + wy) * 64 + blockIdx.x * 8 + wx;
            var_out[(size_t)b * NW_ + n] = s2 * (1.0 / 63.0);
        }
    }
}

// ---------------------------------------------------------------------------
// CA: reduce pooled partials (256 blocks/batch) -> 1x1 conv -> sigmoid
// ---------------------------------------------------------------------------
__global__ __launch_bounds__(256) void ca_kernel(
    const float* __restrict__ pooled_part,
    const float* __restrict__ w_ca, const float* __restrict__ b_ca,
    float* __restrict__ ca_out)
{
    __shared__ float pooled[64];
    const int t = threadIdx.x;
    if (t < 64) {
        const int b = t >> 3, q = t & 7;
        float s = 0.f;
        for (int k = 0; k < 256; ++k) s += pooled_part[(b * 256 + k) * CQ_ + q];
        pooled[t] = s * (1.f / ((float)H_ * (float)W_));
    }
    __syncthreads();
    const int b = t >> 5, o = t & 31;
    float acc = b_ca[o];
#pragma unroll
    for (int q = 0; q < CQ_; ++q)
        acc = fmaf(w_ca[o * CQ_ + q], pooled[b * CQ_ + q], acc);
    ca_out[t] = sigmoidf_(acc);
}

// ---------------------------------------------------------------------------
// Exact bottom-k selection via rank, top_k-stable tie-break. grid (16, B)
// ---------------------------------------------------------------------------
__global__ __launch_bounds__(256) void mask_rank(const double* __restrict__ var,
                                                 float* __restrict__ maskF)
{
    __shared__ double sv[NW_];   // 32 KB
    const int b = blockIdx.y;
    const int tid = threadIdx.x;
    const double* vb = var + (size_t)b * NW_;
    for (int j = tid; j < NW_; j += 256) sv[j] = vb[j];
    __syncthreads();

    const int i = blockIdx.x * 256 + tid;
    const double vi = sv[i];
    int cnt = 0;
#pragma unroll 4
    for (int j = 0; j < NW_; ++j) {
        const double vj = sv[j];
        cnt += (vj < vi) || (vj == vi && j < i);
    }
    maskF[(size_t)b * NW_ + i] = (cnt < NW_ / 2) ? 0.f : 1.f;
}

// ---------------------------------------------------------------------------
// h1[e] = leaky(rowsum(w_m1[e,:]) + b_m1[e]);  h0[e] = leaky(b_m1[e])
// ---------------------------------------------------------------------------
__global__ __launch_bounds__(256) void h_kernel(const float* __restrict__ w_m1,
                                                const float* __restrict__ b_m1,
                                                float* __restrict__ h1, float* __restrict__ h0)
{
    const int wave = threadIdx.x >> 6, lane = threadIdx.x & 63;
    const int e = blockIdx.x * 4 + wave;
    const float* row = w_m1 + (size_t)e * ED_;
    float s = 0.f;
#pragma unroll
    for (int k = 0; k < ED_ / 64; ++k) s += row[lane + 64 * k];
#pragma unroll
    for (int off = 32; off; off >>= 1) s += __shfl_xor(s, off);
    if (lane == 0) {
        h1[e] = leaky(s + b_m1[e]);
        h0[e] = leaky(b_m1[e]);
    }
}

// ---------------------------------------------------------------------------
// o1[f] = w_m2[f,:].h1 + b_m2[f];  o0[f] = w_m2[f,:].h0 + b_m2[f]
// ---------------------------------------------------------------------------
__global__ __launch_bounds__(256) void o_kernel(const float* __restrict__ w_m2,
                                                const float* __restrict__ b_m2,
                                                const float* __restrict__ h1,
                                                const float* __restrict__ h0,
                                                float* __restrict__ o1, float* __restrict__ o0)
{
    const int wave = threadIdx.x >> 6, lane = threadIdx.x & 63;
    const int f = blockIdx.x * 4 + wave;
    const float* row = w_m2 + (size_t)f * EH_;
    float s1 = 0.f, s0 = 0.f;
#pragma unroll
    for (int k = 0; k < EH_ / 64; ++k) {
        const float w = row[lane + 64 * k];
        s1 = fmaf(w, h1[lane + 64 * k], s1);
        s0 = fmaf(w, h0[lane + 64 * k], s0);
    }
#pragma unroll
    for (int off = 32; off; off >>= 1) {
        s1 += __shfl_xor(s1, off);
        s0 += __shfl_xor(s0, off);
    }
    if (lane == 0) {
        o1[f] = s1 + b_m2[f];
        o0[f] = s0 + b_m2[f];
    }
}

// ---------------------------------------------------------------------------
// out_mask row = mask ? o1 : o0.  grid 2048, 16 rows/block, rows in regs.
// ---------------------------------------------------------------------------
__global__ __launch_bounds__(256) void bcast_kernel(const float* __restrict__ maskF,
                                                    const float* __restrict__ o1,
                                                    const float* __restrict__ o0,
                                                    float* __restrict__ out)
{
    __shared__ float sm[16];
    const int t = threadIdx.x;
    const long row0 = (long)blockIdx.x * 16;
    if (t < 16) sm[t] = maskF[row0 + t];
    const float4 a1 = ((const float4*)o1)[t], b1 = ((const float4*)o1)[t + 256];
    const float4 a0 = ((const float4*)o0)[t], b0 = ((const float4*)o0)[t + 256];
    __syncthreads();
#pragma unroll
    for (int r = 0; r < 16; ++r) {
        float4* dst = (float4*)(out + (size_t)(row0 + r) * ED_);
        const bool m = sm[r] > 0.5f;
        dst[t]       = m ? a1 : a0;
        dst[t + 256] = m ? b1 : b0;
    }
}

extern "C" void kernel_launch(void* const* d_in, const int* in_sizes, int n_in,
                              void* d_out, int out_size, void* d_ws, size_t ws_size,
                              hipStream_t stream)
{
    const float* x    = (const float*)d_in[0];
    const float* w_in = (const float*)d_in[1];
    const float* b_in = (const float*)d_in[2];
    const float* w_cv = (const float*)d_in[3];
    const float* b_cv = (const float*)d_in[4];
    const float* lnw  = (const float*)d_in[5];
    const float* lnb  = (const float*)d_in[6];
    const float* w_ca = (const float*)d_in[7];
    const float* b_ca = (const float*)d_in[8];
    const float* w_sa = (const float*)d_in[9];
    const float* b_sa = (const float*)d_in[10];
    const float* w_m1 = (const float*)d_in[11];
    const float* b_m1 = (const float*)d_in[12];
    const float* w_m2 = (const float*)d_in[13];
    const float* b_m2 = (const float*)d_in[14];

    float* out_mask = (float*)d_out;                           // [B, NW, ED]
    float* ca_out   = out_mask + (size_t)B_ * NW_ * ED_;       // [B, C]
    float* sa_out   = ca_out + (size_t)B_ * C_;                // [B, H, W]

    char* ws = (char*)d_ws;
    double* var       = (double*)ws;                           // 256 KB
    float*  maskF     = (float*)(ws + (size_t)B_ * NW_ * 8);   // 128 KB
    float*  pooled_pp = maskF + (size_t)B_ * NW_;              // 2048*8 floats = 64 KB
    float*  h1 = pooled_pp + 2048 * CQ_;
    float*  h0 = h1 + EH_;
    float*  o1 = h0 + EH_;
    float*  o0 = o1 + ED_;

    pass_a<<<dim3(W_ / TW, H_ / TH, B_), 256, 0, stream>>>(
        x, w_in, b_in, w_cv, b_cv, lnw, lnb, w_sa, b_sa, sa_out, var, pooled_pp);
    ca_kernel<<<1, 256, 0, stream>>>(pooled_pp, w_ca, b_ca, ca_out);
    mask_rank<<<dim3(NW_ / 256, B_), 256, 0, stream>>>(var, maskF);
    h_kernel<<<EH_ / 4, 256, 0, stream>>>(w_m1, b_m1, h1, h0);
    o_kernel<<<ED_ / 4, 256, 0, stream>>>(w_m2, b_m2, h1, h0, o1, o0);
    bcast_kernel<<<B_ * NW_ / 16, 256, 0, stream>>>(maskF, o1, o0, out_mask);
}